// Round 1
// baseline (429.740 us; speedup 1.0000x reference)
//
#include <hip/hip_runtime.h>
#include <hip/hip_bf16.h>
#include <stdint.h>

#define T_SEQ 4096
#define NH 12

typedef __attribute__((ext_vector_type(4))) float f32x4;
typedef __attribute__((ext_vector_type(8))) __bf16 bf16x8;

__device__ inline ushort f2b(float f) {
  __hip_bfloat16 h = __float2bfloat16(f);
  return *reinterpret_cast<ushort*>(&h);
}

__device__ inline void gload_lds16(const void* g, void* lds) {
  auto g1 = (const __attribute__((address_space(1))) uint32_t*)(uintptr_t)g;
  auto l3 = (__attribute__((address_space(3))) uint32_t*)(uintptr_t)lds;
  __builtin_amdgcn_global_load_lds(g1, l3, 16, 0, 0);
}

// ---------------- fp32 -> bf16 convert ----------------
__global__ void f32_to_bf16(const float* __restrict__ src, ushort* __restrict__ dst, int n) {
  int i = blockIdx.x * blockDim.x + threadIdx.x;
  if (i < n) dst[i] = f2b(src[i]);
}

// ---------------- RoPE tables ----------------
__global__ void rope_tables(float* __restrict__ cosT, float* __restrict__ sinT) {
  int i = blockIdx.x * blockDim.x + threadIdx.x;  // t*32 + d
  if (i >= T_SEQ * 32) return;
  int t = i >> 5, d = i & 31;
  float theta = 1.0f / powf(10000.0f, (float)d * (1.0f / 32.0f));
  float a = (float)t * theta;
  cosT[i] = cosf(a);
  sinT[i] = sinf(a);
}

// ---------------- RoPE apply + reorder ----------------
// qkv fp32 [T][2304] -> Q,K bf16 [H][T][64] (roped), Vt bf16 [H][64][T]
__global__ void rope_reorder(const float* __restrict__ qkv,
                             const float* __restrict__ cosT, const float* __restrict__ sinT,
                             ushort* __restrict__ Q, ushort* __restrict__ Kb, ushort* __restrict__ Vt) {
  const int tq = blockIdx.x;
  const int h  = blockIdx.y;
  const int d  = threadIdx.x;     // 0..63
  const int dd = d & 31;
  const float* row = qkv + (long)tq * 2304 + h * 64;
  const float cs = cosT[tq * 32 + dd], sn = sinT[tq * 32 + dd];
  float q1 = row[dd],       q2 = row[dd + 32];
  float k1 = row[768 + dd], k2 = row[768 + dd + 32];
  float qv = (d < 32) ? (q1 * cs - q2 * sn) : (q1 * sn + q2 * cs);
  float kv = (d < 32) ? (k1 * cs - k2 * sn) : (k1 * sn + k2 * cs);
  float vv = row[1536 + d];
  long base = ((long)h * T_SEQ + tq) * 64 + d;
  Q[base]  = f2b(qv);
  Kb[base] = f2b(kv);
  Vt[((long)h * 64 + d) * T_SEQ + tq] = f2b(vv);
}

// ---------------- bf16 GEMM, C = A * B^T ----------------
// A: [M][K] bf16, B: [N][K] bf16, C: [M][N] fp32. M%128==0, N%128==0, K%64==0.
__global__ __launch_bounds__(256) void gemm_bt(const ushort* __restrict__ A,
                                               const ushort* __restrict__ B,
                                               float* __restrict__ C,
                                               int M, int N, int K) {
  __shared__ ushort As[128 * 64];
  __shared__ ushort Bs[128 * 64];
  const int t = threadIdx.x;
  const int w = t >> 6, l = t & 63;
  const int lo = l & 15, hi = l >> 4;
  const int wr = w >> 1, wc = w & 1;
  const long arow = (long)blockIdx.y * 128;
  const long brow = (long)blockIdx.x * 128;
  f32x4 acc[4][4] = {};
  for (int k0 = 0; k0 < K; k0 += 64) {
    for (int i = 0; i < 4; ++i) {
      int e = i * 2048 + t * 8;          // element idx in [128][64] tile
      int r = e >> 6, c = e & 63;
      const ushort* ga = A + (arow + r) * (long)K + k0 + c;
      const ushort* gb = B + (brow + r) * (long)K + k0 + c;
      uint32_t ldsoff = i * 4096 + w * 1024;  // bytes, wave-uniform
      gload_lds16(ga, (char*)As + ldsoff);
      gload_lds16(gb, (char*)Bs + ldsoff);
    }
    __syncthreads();
    for (int kk = 0; kk < 2; ++kk) {
      bf16x8 af[4], bfr[4];
      for (int m = 0; m < 4; ++m)
        af[m] = *(const bf16x8*)&As[(wr * 64 + m * 16 + lo) * 64 + kk * 32 + hi * 8];
      for (int n = 0; n < 4; ++n)
        bfr[n] = *(const bf16x8*)&Bs[(wc * 64 + n * 16 + lo) * 64 + kk * 32 + hi * 8];
      for (int m = 0; m < 4; ++m)
        for (int n = 0; n < 4; ++n)
          acc[m][n] = __builtin_amdgcn_mfma_f32_16x16x32_bf16(af[m], bfr[n], acc[m][n], 0, 0, 0);
    }
    __syncthreads();
  }
  for (int m = 0; m < 4; ++m) {
    long row0 = arow + wr * 64 + m * 16 + hi * 4;
    for (int n = 0; n < 4; ++n) {
      long col = brow + wc * 64 + n * 16 + lo;
      for (int r = 0; r < 4; ++r)
        C[(row0 + r) * (long)N + col] = acc[m][n][r];
    }
  }
}

// ---------------- flash attention ----------------
// Q,K: [H][T][64] bf16 (roped), Vt: [H][64][T] bf16, Y: [T][768] bf16
__global__ __launch_bounds__(256) void flash_attn(const ushort* __restrict__ Q,
                                                  const ushort* __restrict__ Kb,
                                                  const ushort* __restrict__ Vt,
                                                  ushort* __restrict__ Y) {
  const int h  = blockIdx.y;
  const int qb = blockIdx.x;
  const int t  = threadIdx.x;
  const int w  = t >> 6, l = t & 63;
  const int lo = l & 15, hi = l >> 4;
  const int qrow0 = qb * 64 + w * 16;
  __shared__ ushort P[4][16][40];   // per-wave P tile, padded stride 40 (80B, 16B-aligned rows)

  bf16x8 qf[2];
  {
    const ushort* qp = Q + ((long)h * T_SEQ + qrow0 + lo) * 64 + hi * 8;
    qf[0] = *(const bf16x8*)qp;
    qf[1] = *(const bf16x8*)(qp + 32);
  }
  f32x4 o[4] = {};
  float mrun[4], lrun[4];
  for (int r = 0; r < 4; ++r) { mrun[r] = -1e30f; lrun[r] = 0.0f; }

  const int nkb = (qrow0 + 16 + 31) >> 5;   // causal limit for this wave
  for (int kb = 0; kb < nkb; ++kb) {
    const int k0 = kb * 32;
    float p[2][4];
    float mt[4] = {-1e30f, -1e30f, -1e30f, -1e30f};
    for (int cb = 0; cb < 2; ++cb) {
      f32x4 s = {};
      const ushort* kp = Kb + ((long)h * T_SEQ + k0 + cb * 16 + lo) * 64 + hi * 8;
      s = __builtin_amdgcn_mfma_f32_16x16x32_bf16(qf[0], *(const bf16x8*)kp, s, 0, 0, 0);
      s = __builtin_amdgcn_mfma_f32_16x16x32_bf16(qf[1], *(const bf16x8*)(kp + 32), s, 0, 0, 0);
      const int key = k0 + cb * 16 + lo;
      for (int r = 0; r < 4; ++r) {
        float v = s[r] * 0.125f;
        v = (key <= qrow0 + hi * 4 + r) ? v : -1e30f;
        p[cb][r] = v;
        mt[r] = fmaxf(mt[r], v);
      }
    }
    for (int j = 1; j < 16; j <<= 1)
      for (int r = 0; r < 4; ++r)
        mt[r] = fmaxf(mt[r], __shfl_xor(mt[r], j));
    float alpha[4], ps[4] = {0, 0, 0, 0};
    for (int r = 0; r < 4; ++r) {
      float mn = fmaxf(mrun[r], mt[r]);
      alpha[r] = __expf(mrun[r] - mn);
      mrun[r] = mn;
    }
    for (int cb = 0; cb < 2; ++cb)
      for (int r = 0; r < 4; ++r) {
        float e = __expf(p[cb][r] - mrun[r]);
        p[cb][r] = e;
        ps[r] += e;
      }
    for (int j = 1; j < 16; j <<= 1)
      for (int r = 0; r < 4; ++r)
        ps[r] += __shfl_xor(ps[r], j);
    for (int r = 0; r < 4; ++r)
      lrun[r] = lrun[r] * alpha[r] + ps[r];
    for (int cb = 0; cb < 4; ++cb)
      for (int r = 0; r < 4; ++r)
        o[cb][r] *= alpha[r];
    // P -> LDS (bf16), transpose bounce for PV A-fragment
    for (int cb = 0; cb < 2; ++cb)
      for (int r = 0; r < 4; ++r)
        P[w][hi * 4 + r][cb * 16 + lo] = f2b(p[cb][r]);
    asm volatile("s_waitcnt lgkmcnt(0)" ::: "memory");
    bf16x8 pa = *(const bf16x8*)&P[w][lo][hi * 8];
    for (int cb = 0; cb < 4; ++cb) {
      const ushort* vp = Vt + ((long)h * 64 + cb * 16 + lo) * T_SEQ + k0 + hi * 8;
      o[cb] = __builtin_amdgcn_mfma_f32_16x16x32_bf16(pa, *(const bf16x8*)vp, o[cb], 0, 0, 0);
    }
    asm volatile("s_waitcnt lgkmcnt(0)" ::: "memory");
  }
  for (int r = 0; r < 4; ++r) {
    float inv = 1.0f / lrun[r];
    long row = qrow0 + hi * 4 + r;
    for (int cb = 0; cb < 4; ++cb)
      Y[row * 768 + h * 64 + cb * 16 + lo] = f2b(o[cb][r] * inv);
  }
}

extern "C" void kernel_launch(void* const* d_in, const int* in_sizes, int n_in,
                              void* d_out, int out_size, void* d_ws, size_t ws_size,
                              hipStream_t stream) {
  const float* x      = (const float*)d_in[0];
  const float* w_attn = (const float*)d_in[1];
  const float* w_proj = (const float*)d_in[2];
  float* out = (float*)d_out;
  char* ws = (char*)d_ws;

  ushort* xb   = (ushort*)(ws);                 // 4096*768
  ushort* wAb  = (ushort*)(ws + 6291456);       // 2304*768
  ushort* wPb  = (ushort*)(ws + 9830400);       // 768*768
  float*  cosT = (float*)(ws + 11010048);       // 4096*32
  float*  sinT = (float*)(ws + 11534336);
  float*  qkv  = (float*)(ws + 12058624);       // 4096*2304 fp32
  ushort* Qb   = (ushort*)(ws + 49807360);      // [12][4096][64]
  ushort* Kbb  = (ushort*)(ws + 56098816);
  ushort* Vt   = (ushort*)(ws + 62390272);      // [12][64][4096]
  ushort* Yb   = (ushort*)(ws + 68681728);      // [4096][768]

  f32_to_bf16<<<(3145728 + 255) / 256, 256, 0, stream>>>(x, xb, 3145728);
  f32_to_bf16<<<(1769472 + 255) / 256, 256, 0, stream>>>(w_attn, wAb, 1769472);
  f32_to_bf16<<<(589824 + 255) / 256, 256, 0, stream>>>(w_proj, wPb, 589824);
  rope_tables<<<(131072 + 255) / 256, 256, 0, stream>>>(cosT, sinT);

  gemm_bt<<<dim3(2304 / 128, 4096 / 128), 256, 0, stream>>>(xb, wAb, qkv, 4096, 2304, 768);
  rope_reorder<<<dim3(T_SEQ, NH), 64, 0, stream>>>(qkv, cosT, sinT, Qb, Kbb, Vt);
  flash_attn<<<dim3(T_SEQ / 64, NH), 256, 0, stream>>>(Qb, Kbb, Vt, Yb);
  gemm_bt<<<dim3(768 / 128, 4096 / 128), 256, 0, stream>>>(Yb, wPb, out, 4096, 768, 768);
}

// Round 2
// 298.456 us; speedup vs baseline: 1.4399x; 1.4399x over previous
//
#include <hip/hip_runtime.h>
#include <hip/hip_bf16.h>
#include <stdint.h>

#define T_SEQ 4096
#define NH 12

typedef __attribute__((ext_vector_type(4))) float f32x4;
typedef __attribute__((ext_vector_type(8))) __bf16 bf16x8;

__device__ inline ushort f2b(float f) {
  __hip_bfloat16 h = __float2bfloat16(f);
  return *reinterpret_cast<ushort*>(&h);
}

__device__ inline void gload_lds16(const void* g, void* lds) {
  auto g1 = (const __attribute__((address_space(1))) uint32_t*)(uintptr_t)g;
  auto l3 = (__attribute__((address_space(3))) uint32_t*)(uintptr_t)lds;
  __builtin_amdgcn_global_load_lds(g1, l3, 16, 0, 0);
}

// ---------------- fp32 -> bf16 convert ----------------
__global__ void f32_to_bf16(const float* __restrict__ src, ushort* __restrict__ dst, int n) {
  int i = blockIdx.x * blockDim.x + threadIdx.x;
  if (i < n) dst[i] = f2b(src[i]);
}

// ---------------- RoPE tables ----------------
__global__ void rope_tables(float* __restrict__ cosT, float* __restrict__ sinT) {
  int i = blockIdx.x * blockDim.x + threadIdx.x;  // t*32 + d
  if (i >= T_SEQ * 32) return;
  int t = i >> 5, d = i & 31;
  float theta = 1.0f / powf(10000.0f, (float)d * (1.0f / 32.0f));
  float a = (float)t * theta;
  cosT[i] = cosf(a);
  sinT[i] = sinf(a);
}

// ---------------- RoPE apply + reorder ----------------
// qkv fp32 [T][2304] -> Q (roped, scaled by 1/8), K (roped) bf16 [H][T][64], Vt bf16 [H][64][T]
__global__ void rope_reorder(const float* __restrict__ qkv,
                             const float* __restrict__ cosT, const float* __restrict__ sinT,
                             ushort* __restrict__ Q, ushort* __restrict__ Kb, ushort* __restrict__ Vt) {
  const int tq = blockIdx.x;
  const int h  = blockIdx.y;
  const int d  = threadIdx.x;     // 0..63
  const int dd = d & 31;
  const float* row = qkv + (long)tq * 2304 + h * 64;
  const float cs = cosT[tq * 32 + dd], sn = sinT[tq * 32 + dd];
  float q1 = row[dd],       q2 = row[dd + 32];
  float k1 = row[768 + dd], k2 = row[768 + dd + 32];
  float qv = (d < 32) ? (q1 * cs - q2 * sn) : (q1 * sn + q2 * cs);
  float kv = (d < 32) ? (k1 * cs - k2 * sn) : (k1 * sn + k2 * cs);
  float vv = row[1536 + d];
  long base = ((long)h * T_SEQ + tq) * 64 + d;
  Q[base]  = f2b(qv * 0.125f);    // fold 1/sqrt(D) into Q
  Kb[base] = f2b(kv);
  Vt[((long)h * 64 + d) * T_SEQ + tq] = f2b(vv);
}

// ---------------- bf16 GEMM, C = A * B^T ----------------
__global__ __launch_bounds__(256) void gemm_bt(const ushort* __restrict__ A,
                                               const ushort* __restrict__ B,
                                               float* __restrict__ C,
                                               int M, int N, int K) {
  __shared__ ushort As[128 * 64];
  __shared__ ushort Bs[128 * 64];
  const int t = threadIdx.x;
  const int w = t >> 6, l = t & 63;
  const int lo = l & 15, hi = l >> 4;
  const int wr = w >> 1, wc = w & 1;
  const long arow = (long)blockIdx.y * 128;
  const long brow = (long)blockIdx.x * 128;
  f32x4 acc[4][4] = {};
  for (int k0 = 0; k0 < K; k0 += 64) {
    for (int i = 0; i < 4; ++i) {
      int e = i * 2048 + t * 8;
      int r = e >> 6, c = e & 63;
      const ushort* ga = A + (arow + r) * (long)K + k0 + c;
      const ushort* gb = B + (brow + r) * (long)K + k0 + c;
      uint32_t ldsoff = i * 4096 + w * 1024;
      gload_lds16(ga, (char*)As + ldsoff);
      gload_lds16(gb, (char*)Bs + ldsoff);
    }
    __syncthreads();
    for (int kk = 0; kk < 2; ++kk) {
      bf16x8 af[4], bfr[4];
      for (int m = 0; m < 4; ++m)
        af[m] = *(const bf16x8*)&As[(wr * 64 + m * 16 + lo) * 64 + kk * 32 + hi * 8];
      for (int n = 0; n < 4; ++n)
        bfr[n] = *(const bf16x8*)&Bs[(wc * 64 + n * 16 + lo) * 64 + kk * 32 + hi * 8];
      for (int m = 0; m < 4; ++m)
        for (int n = 0; n < 4; ++n)
          acc[m][n] = __builtin_amdgcn_mfma_f32_16x16x32_bf16(af[m], bfr[n], acc[m][n], 0, 0, 0);
    }
    __syncthreads();
  }
  for (int m = 0; m < 4; ++m) {
    long row0 = arow + wr * 64 + m * 16 + hi * 4;
    for (int n = 0; n < 4; ++n) {
      long col = brow + wc * 64 + n * 16 + lo;
      for (int r = 0; r < 4; ++r)
        C[(row0 + r) * (long)N + col] = acc[m][n][r];
    }
  }
}

// ---------------- flash attention (swapped QK^T, KVBLK=64) ----------------
// Q: [H][T][64] bf16 (roped, pre-scaled), K: [H][T][64] bf16, Vt: [H][64][T] bf16, Y: [T][768] bf16
// 2 waves/block, 16 q-rows/wave. Swapped S^T = mfma(K, Q): lane holds ONE q-row (col=lo)
// and 16 keys (row = kt*16 + hi*4 + r) -> softmax row-reduce is in-register + 2 shfl.
__global__ __launch_bounds__(128) void flash_attn(const ushort* __restrict__ Q,
                                                  const ushort* __restrict__ Kb,
                                                  const ushort* __restrict__ Vt,
                                                  ushort* __restrict__ Y) {
  const int idx = blockIdx.x;           // 1536 blocks, longest first
  const int h   = idx % NH;
  const int qg  = 127 - idx / NH;       // 32-row q-group, descending (LPT)
  const int w   = threadIdx.x >> 6, l = threadIdx.x & 63;
  const int lo  = l & 15, hi = l >> 4;
  const int qrow0 = qg * 32 + w * 16;
  const int qabs  = qrow0 + lo;         // q-row owned by this lane for softmax
  __shared__ ushort P[2][16][72];       // per-wave P tile [qrow][key], pad to 72

  const long hT   = (long)h * T_SEQ;
  const long hT64 = (long)h * 64;
  bf16x8 qf0, qf1;
  {
    const ushort* qp = Q + (hT + qrow0 + lo) * 64 + hi * 8;
    qf0 = *(const bf16x8*)qp;
    qf1 = *(const bf16x8*)(qp + 32);
  }
  f32x4 o[4] = {};
  float m = -1e30f, lsum = 0.0f;

  const int nkb = (qrow0 + 16 + 63) >> 6;
  for (int kb = 0; kb < nkb; ++kb) {
    const int k0 = kb * 64;
    // --- S^T[key][qrow] = K . Q^T ---
    f32x4 s[4];
    for (int kt = 0; kt < 4; ++kt) {
      const ushort* kp = Kb + (hT + k0 + kt * 16 + lo) * 64 + hi * 8;
      f32x4 acc = {};
      acc = __builtin_amdgcn_mfma_f32_16x16x32_bf16(*(const bf16x8*)kp, qf0, acc, 0, 0, 0);
      acc = __builtin_amdgcn_mfma_f32_16x16x32_bf16(*(const bf16x8*)(kp + 32), qf1, acc, 0, 0, 0);
      s[kt] = acc;
    }
    // --- causal mask (wave-uniform branch; only partial blocks) ---
    if (k0 + 64 > qrow0) {
      for (int kt = 0; kt < 4; ++kt)
        for (int r = 0; r < 4; ++r) {
          int key = k0 + kt * 16 + hi * 4 + r;
          if (key > qabs) s[kt][r] = -1e30f;
        }
    }
    // --- row max: 15 in-lane fmax + 2 shfl ---
    float mt = s[0][0];
    for (int kt = 0; kt < 4; ++kt)
      for (int r = 0; r < 4; ++r) mt = fmaxf(mt, s[kt][r]);
    mt = fmaxf(mt, __shfl_xor(mt, 16));
    mt = fmaxf(mt, __shfl_xor(mt, 32));
    const float mn = fmaxf(m, mt);
    const float alpha = __expf(m - mn);
    m = mn;
    // --- exp + row sum + pack P ---
    float psum = 0.0f;
    for (int kt = 0; kt < 4; ++kt) {
      float p0 = __expf(s[kt][0] - mn);
      float p1 = __expf(s[kt][1] - mn);
      float p2 = __expf(s[kt][2] - mn);
      float p3 = __expf(s[kt][3] - mn);
      psum += (p0 + p1) + (p2 + p3);
      uint2 pk;
      pk.x = (uint)f2b(p0) | ((uint)f2b(p1) << 16);
      pk.y = (uint)f2b(p2) | ((uint)f2b(p3) << 16);
      *(uint2*)&P[w][lo][kt * 16 + hi * 4] = pk;
    }
    psum += __shfl_xor(psum, 16);
    psum += __shfl_xor(psum, 32);
    lsum = lsum * alpha + psum;
    // --- rescale O (deliver alpha from qrow=lo layout to qrow=hi*4+r layout) ---
    for (int r = 0; r < 4; ++r) {
      float ar = __shfl(alpha, hi * 4 + r);
      for (int dt = 0; dt < 4; ++dt) o[dt][r] *= ar;
    }
    // --- PV: O += P . V ---
    for (int c = 0; c < 2; ++c) {
      bf16x8 pa = *(const bf16x8*)&P[w][lo][c * 32 + hi * 8];
      for (int dt = 0; dt < 4; ++dt) {
        const ushort* vp = Vt + (hT64 + dt * 16 + lo) * T_SEQ + k0 + c * 32 + hi * 8;
        o[dt] = __builtin_amdgcn_mfma_f32_16x16x32_bf16(pa, *(const bf16x8*)vp, o[dt], 0, 0, 0);
      }
    }
  }
  // --- normalize + write ---
  const float inv = 1.0f / lsum;
  for (int r = 0; r < 4; ++r) {
    float ir = __shfl(inv, hi * 4 + r);
    long row = qrow0 + hi * 4 + r;
    for (int dt = 0; dt < 4; ++dt)
      Y[row * 768 + h * 64 + dt * 16 + lo] = f2b(o[dt][r] * ir);
  }
}

extern "C" void kernel_launch(void* const* d_in, const int* in_sizes, int n_in,
                              void* d_out, int out_size, void* d_ws, size_t ws_size,
                              hipStream_t stream) {
  const float* x      = (const float*)d_in[0];
  const float* w_attn = (const float*)d_in[1];
  const float* w_proj = (const float*)d_in[2];
  float* out = (float*)d_out;
  char* ws = (char*)d_ws;

  ushort* xb   = (ushort*)(ws);                 // 4096*768
  ushort* wAb  = (ushort*)(ws + 6291456);       // 2304*768
  ushort* wPb  = (ushort*)(ws + 9830400);       // 768*768
  float*  cosT = (float*)(ws + 11010048);       // 4096*32
  float*  sinT = (float*)(ws + 11534336);
  float*  qkv  = (float*)(ws + 12058624);       // 4096*2304 fp32
  ushort* Qb   = (ushort*)(ws + 49807360);      // [12][4096][64]
  ushort* Kbb  = (ushort*)(ws + 56098816);
  ushort* Vt   = (ushort*)(ws + 62390272);      // [12][64][4096]
  ushort* Yb   = (ushort*)(ws + 68681728);      // [4096][768]

  f32_to_bf16<<<(3145728 + 255) / 256, 256, 0, stream>>>(x, xb, 3145728);
  f32_to_bf16<<<(1769472 + 255) / 256, 256, 0, stream>>>(w_attn, wAb, 1769472);
  f32_to_bf16<<<(589824 + 255) / 256, 256, 0, stream>>>(w_proj, wPb, 589824);
  rope_tables<<<(131072 + 255) / 256, 256, 0, stream>>>(cosT, sinT);

  gemm_bt<<<dim3(2304 / 128, 4096 / 128), 256, 0, stream>>>(xb, wAb, qkv, 4096, 2304, 768);
  rope_reorder<<<dim3(T_SEQ, NH), 64, 0, stream>>>(qkv, cosT, sinT, Qb, Kbb, Vt);
  flash_attn<<<128 * NH, 128, 0, stream>>>(Qb, Kbb, Vt, Yb);
  gemm_bt<<<dim3(768 / 128, 4096 / 128), 256, 0, stream>>>(Yb, wPb, out, 4096, 768, 768);
}